// Round 11
// baseline (213.907 us; speedup 1.0000x reference)
//
#include <hip/hip_runtime.h>

// MultiHeadSelfAttention: B=2, S=2048, E=1024, H=16, D=64
// bf16 MFMA pipeline. R11: gemm1 BK=64 (half the barriers), V written
// directly transposed from gemm1's epilogue (transpose_v kernel removed,
// qkvb V-columns never written). attn frozen from R10.

typedef unsigned short u16;
typedef short bf16x8 __attribute__((ext_vector_type(8)));
typedef float f32x4 __attribute__((ext_vector_type(4)));
typedef unsigned short u16x4 __attribute__((ext_vector_type(4)));

#define S_LEN 2048
#define EMB 1024
#define NH 16
#define HD 64
#define QKV_W 3072
#define BATCH 2
#define CSC 0.18033688f  // 0.125 * log2(e)
#define PSTR 72          // plds row stride (64-wide P rows)

static __device__ __forceinline__ u16 f2bf(float f) {
    unsigned x = __float_as_uint(f);
    return (u16)((x + 0x7fffu + ((x >> 16) & 1u)) >> 16);
}

static __device__ __forceinline__ void gld_lds16(const u16* g, u16* l) {
    __builtin_amdgcn_global_load_lds(
        (const __attribute__((address_space(1))) void*)g,
        (__attribute__((address_space(3))) void*)l, 16, 0, 0);
}

// ---------------- fused fp32 -> bf16 casts (3 ranges) ----------------
#define XN4 (BATCH * S_LEN * EMB / 4)      // 1048576
#define WQ4 (QKV_W * EMB / 4)              // 786432
#define W04 (EMB * EMB / 4)                // 262144
__global__ __launch_bounds__(256) void cvt_all(const float* __restrict__ x,
                                               const float* __restrict__ wq,
                                               const float* __restrict__ w0,
                                               u16* __restrict__ xb,
                                               u16* __restrict__ wqb,
                                               u16* __restrict__ w0b) {
    int i = blockIdx.x * 256 + threadIdx.x;
    const float* src;
    u16* dst;
    int off;
    if (i < XN4) { src = x; dst = xb; off = i; }
    else if (i < XN4 + WQ4) { src = wq; dst = wqb; off = i - XN4; }
    else { src = w0; dst = w0b; off = i - XN4 - WQ4; }
    float4 v = ((const float4*)src)[off];
    u16x4 o;
    o[0] = f2bf(v.x); o[1] = f2bf(v.y); o[2] = f2bf(v.z); o[3] = f2bf(v.w);
    ((u16x4*)dst)[off] = o;
}

// ---------------- GEMM: C[M,N] = A[M,K] @ Bt[N,K]^T ----------------
// BM=128, BN/BK templated, 256 thr / 4 waves.
// Columns n < qcols scaled by CSC (Q pre-scaling for attention).
// If vt != nullptr, blocks with n0 >= 2048 write V transposed into
// vt[((b*16+h)*64+d)*2048 + s] instead of C (and skip the C write).
template <typename OutT, int BN, int BK>
__global__ __launch_bounds__(256) void gemm_bt(const u16* __restrict__ A,
                                               const u16* __restrict__ Bt,
                                               OutT* __restrict__ C,
                                               u16* __restrict__ vt,
                                               int M, int N, int K, int qcols) {
    constexpr int NF = BN / 32;           // n-frags per wave
    constexpr int KH = BK / 32;           // k-halves per LDS tile
    constexpr int ACH = 128 * BK / 2048;  // A staging chunks per thread
    constexpr int BCH = BN * BK / 2048;   // B staging chunks per thread
    __shared__ alignas(16) u16 As[128 * BK];
    __shared__ alignas(16) u16 Bs[BN * BK];
    const int tid = threadIdx.x;
    const int wave = tid >> 6, lane = tid & 63;
    const int quad = lane >> 4, lr = lane & 15;
    const int m0 = blockIdx.y * 128, n0 = blockIdx.x * BN;
    const int wm = (wave & 1) * 64, wn = (wave >> 1) * (BN / 2);
    const float sc = (n0 < qcols) ? CSC : 1.0f;

    f32x4 acc[4][NF] = {};

    for (int k0 = 0; k0 < K; k0 += BK) {
#pragma unroll
        for (int i = 0; i < ACH; ++i) {
            int chunk = tid + i * 256;
            int row = chunk / (BK / 8);
            int col8 = (chunk % (BK / 8)) * 8;
            gld_lds16(&A[(size_t)(m0 + row) * K + k0 + col8], &As[row * BK + col8]);
        }
#pragma unroll
        for (int i = 0; i < BCH; ++i) {
            int chunk = tid + i * 256;
            int row = chunk / (BK / 8);
            int col8 = (chunk % (BK / 8)) * 8;
            gld_lds16(&Bt[(size_t)(n0 + row) * K + k0 + col8], &Bs[row * BK + col8]);
        }
        __syncthreads();
#pragma unroll
        for (int kh = 0; kh < KH; ++kh) {
            bf16x8 af[4], bf[NF];
#pragma unroll
            for (int i = 0; i < 4; ++i)
                af[i] = *(const bf16x8*)&As[(wm + i * 16 + lr) * BK + kh * 32 + quad * 8];
#pragma unroll
            for (int i = 0; i < NF; ++i)
                bf[i] = *(const bf16x8*)&Bs[(wn + i * 16 + lr) * BK + kh * 32 + quad * 8];
#pragma unroll
            for (int mi = 0; mi < 4; ++mi)
#pragma unroll
                for (int ni = 0; ni < NF; ++ni)
                    acc[mi][ni] = __builtin_amdgcn_mfma_f32_16x16x32_bf16(
                        af[mi], bf[ni], acc[mi][ni], 0, 0, 0);
        }
        __syncthreads();
    }

    const bool vmode = (vt != nullptr) && (n0 >= 2 * EMB);
#pragma unroll
    for (int mi = 0; mi < 4; ++mi) {
#pragma unroll
        for (int r = 0; r < 4; ++r) {
            int gr = m0 + wm + mi * 16 + quad * 4 + r;
#pragma unroll
            for (int ni = 0; ni < NF; ++ni) {
                int gc = n0 + wn + ni * 16 + lr;
                float v = acc[mi][ni][r] * sc;
                if (vmode) {
                    // V^T scatter: vt[(b*1024 + h*64+d)*2048 + s]
                    int hd = gc - 2 * EMB;
                    vt[((size_t)(gr >> 11) * 1024 + hd) * (size_t)S_LEN +
                       (gr & 2047)] = f2bf(v);
                } else if constexpr (sizeof(OutT) == 2) {
                    C[(size_t)gr * N + gc] = (OutT)f2bf(v);
                } else {
                    C[(size_t)gr * N + gc] = (OutT)v;
                }
            }
        }
    }
}

// ---------------- Flash attention (causal), R10 structure (frozen) ----------------
// grid (16, 32), 512 thr = 8 waves. Pairing {pi, 31-pi}: waves 0-3 own
// tile A=pi, waves 4-7 own tile B=31-pi (132 wave-iters/block, uniform).
// Swizzle keeps co-resident blocks complementary. Double-buffered Ks/Vs,
// one barrier/iter; waves 0-3 stage K, 4-7 stage V; p = exp2(s).
__global__ __launch_bounds__(512, 4) void attn(const u16* __restrict__ qkv,
                                               const u16* __restrict__ vt,
                                               u16* __restrict__ e) {
    const int tid = threadIdx.x;
    const int w = tid >> 6, lane = tid & 63;
    const int quad = lane >> 4, lr = lane & 15;
    const int bx = blockIdx.x, by = blockIdx.y;
    const int flip = (by >> 4) & 1;
    const int pi = flip ? (15 - bx) : bx;
    const int bh = ((by & 15) << 1) | flip;
    const int qtA = pi, qtB = 31 - pi;
    const int b = bh >> 4, h = bh & 15;
    const int myqt = (w < 4) ? qtA : qtB;
    const int qbase = myqt * 64 + (w & 3) * 16;

    __shared__ alignas(16) u16 Ks[2 * 2 * 64 * 32];  // [buf][d-half][kv row][32]
    __shared__ alignas(16) u16 Vs[2 * 2 * 64 * 32];  // [buf][kv-half][d row][32]
    __shared__ alignas(16) u16 plds[8][16 * PSTR];
    u16* pw = plds[w];

    const u16* qkv_b = qkv + (size_t)b * S_LEN * QKV_W;
    const u16* qrow = qkv_b + (size_t)(qbase + lr) * QKV_W + h * HD + quad * 8;
    const bf16x8 qf0 = *(const bf16x8*)(qrow);
    const bf16x8 qf1 = *(const bf16x8*)(qrow + 32);

    const u16* kbase = qkv_b + EMB + h * HD;          // K[s][d], stride 3072
    const u16* vbase = vt + (size_t)bh * HD * S_LEN;  // V^T[d][s], stride 2048

    f32x4 o[4] = {};
    float lsum = 0.f;
    const int qg = qbase + lr;

    // staging role: waves 0-3 -> K rows, waves 4-7 -> V rows
    const int sr = (w & 3) * 16 + (lane >> 2);  // row 0..63
    const int sc = (lane & 3) * 8;              // 0,8,16,24

    auto stage = [&](int j, int bb) {
        const int kv0 = j * 64;
        if (w < 4) {
            gld_lds16(kbase + (size_t)(kv0 + sr) * QKV_W + sc,
                      &Ks[bb * 4096 + sr * 32 + sc]);
            gld_lds16(kbase + (size_t)(kv0 + sr) * QKV_W + 32 + sc,
                      &Ks[bb * 4096 + 2048 + sr * 32 + sc]);
        } else {
            gld_lds16(vbase + (size_t)sr * S_LEN + kv0 + sc,
                      &Vs[bb * 4096 + sr * 32 + sc]);
            gld_lds16(vbase + (size_t)sr * S_LEN + kv0 + 32 + sc,
                      &Vs[bb * 4096 + 2048 + sr * 32 + sc]);
        }
    };

    stage(0, 0);
    for (int j = 0; j <= qtB; ++j) {
        const int bb = j & 1;
        __syncthreads();  // staged buf bb complete (vmcnt drained at barrier)
        if (j < qtB) stage(j + 1, 1 - bb);
        if (j <= myqt) {
            const int kv0 = j * 64;
            const u16* ks = &Ks[bb * 4096];
            const u16* vs = &Vs[bb * 4096];
            // ---- S^T: lane holds S[q=lr][kv=kv0+nt*16+quad*4+r] ----
            f32x4 s[4];
#pragma unroll
            for (int nt = 0; nt < 4; ++nt) {
                bf16x8 k0 = *(const bf16x8*)&ks[(nt * 16 + lr) * 32 + quad * 8];
                bf16x8 k1 = *(const bf16x8*)&ks[2048 + (nt * 16 + lr) * 32 + quad * 8];
                f32x4 z = {};
                z = __builtin_amdgcn_mfma_f32_16x16x32_bf16(k0, qf0, z, 0, 0, 0);
                z = __builtin_amdgcn_mfma_f32_16x16x32_bf16(k1, qf1, z, 0, 0, 0);
                s[nt] = z;
            }
            // ---- softmax: p = exp2(s); mask on the diagonal tile ----
            const bool diag = (j == myqt);
            __builtin_amdgcn_wave_barrier();
#pragma unroll
            for (int nt = 0; nt < 4; ++nt) {
                float p[4];
#pragma unroll
                for (int r = 0; r < 4; ++r) {
                    float pv = exp2f(s[nt][r]);
                    if (diag) pv = (kv0 + nt * 16 + quad * 4 + r > qg) ? 0.f : pv;
                    p[r] = pv;
                }
                lsum += (p[0] + p[1]) + (p[2] + p[3]);
                uint2 pk;  // truncation pack: hi16 of each float
                pk.x = __builtin_amdgcn_perm(__float_as_uint(p[1]),
                                             __float_as_uint(p[0]), 0x07060302u);
                pk.y = __builtin_amdgcn_perm(__float_as_uint(p[3]),
                                             __float_as_uint(p[2]), 0x07060302u);
                *(uint2*)&pw[lr * PSTR + nt * 16 + quad * 4] = pk;
            }
            __builtin_amdgcn_wave_barrier();
            const bf16x8 p0 = *(const bf16x8*)&pw[lr * PSTR + quad * 8];
            const bf16x8 p1 = *(const bf16x8*)&pw[lr * PSTR + 32 + quad * 8];
            // ---- O += P @ V ----
#pragma unroll
            for (int nt = 0; nt < 4; ++nt) {
                bf16x8 v0 = *(const bf16x8*)&vs[(nt * 16 + lr) * 32 + quad * 8];
                bf16x8 v1 = *(const bf16x8*)&vs[2048 + (nt * 16 + lr) * 32 + quad * 8];
                o[nt] = __builtin_amdgcn_mfma_f32_16x16x32_bf16(p0, v0, o[nt], 0, 0, 0);
                o[nt] = __builtin_amdgcn_mfma_f32_16x16x32_bf16(p1, v1, o[nt], 0, 0, 0);
            }
        }
    }

    // ---- finalize: l = quad-reduce(lsum); e = O / l ----
    float lf = lsum + __shfl_xor(lsum, 16, 64);
    lf += __shfl_xor(lf, 32, 64);
#pragma unroll
    for (int r = 0; r < 4; ++r) {
        float inv = 1.0f / __shfl(lf, quad * 4 + r, 64);
        size_t row = (size_t)(b * S_LEN + qbase + quad * 4 + r) * EMB + h * HD;
#pragma unroll
        for (int nt = 0; nt < 4; ++nt)
            e[row + nt * 16 + lr] = f2bf(o[nt][r] * inv);
    }
}

// ---------------- launcher ----------------
extern "C" void kernel_launch(void* const* d_in, const int* in_sizes, int n_in,
                              void* d_out, int out_size, void* d_ws, size_t ws_size,
                              hipStream_t stream) {
    const float* x = (const float*)d_in[0];
    const float* w_qkv = (const float*)d_in[1];
    const float* w0 = (const float*)d_in[2];
    float* out = (float*)d_out;

    const size_t M = (size_t)BATCH * S_LEN;  // 4096
    u16* xb = (u16*)d_ws;
    u16* wqb = xb + M * EMB;
    u16* w0b = wqb + (size_t)QKV_W * EMB;
    u16* qkvb = w0b + (size_t)EMB * EMB;
    u16* vtb = qkvb + M * QKV_W;
    u16* eb = vtb + (size_t)BATCH * NH * HD * S_LEN;

    cvt_all<<<(XN4 + WQ4 + W04) / 256, 256, 0, stream>>>(x, w_qkv, w0, xb, wqb, w0b);

    // qkv = x @ w_qkv^T; Q columns pre-scaled by CSC; V columns written
    // directly transposed into vtb (BK=64: 16 K-iters, 32 MFMA/stage).
    gemm_bt<u16, 128, 64><<<dim3(QKV_W / 128, M / 128), 256, 0, stream>>>(
        xb, wqb, qkvb, vtb, (int)M, QKV_W, EMB, EMB);

    attn<<<dim3(16, BATCH * NH), 512, 0, stream>>>(qkvb, vtb, eb);

    // out = e @ w0^T (128x64 tiles, BK=64 -> 512 blocks, 16 MFMA/barrier)
    gemm_bt<float, 64, 64><<<dim3(EMB / 64, M / 128), 256, 0, stream>>>(
        eb, w0b, out, nullptr, (int)M, EMB, EMB, 0);
}

// Round 12
// 209.395 us; speedup vs baseline: 1.0215x; 1.0215x over previous
//
#include <hip/hip_runtime.h>

// MultiHeadSelfAttention: B=2, S=2048, E=1024, H=16, D=64
// bf16 MFMA pipeline. R12: gemms reverted to R10 (gemm1 BK=32 — BK=64's
// 128-B row stride is a 16-way LDS conflict; transpose_v restored; no V
// scatter). attn rewritten on 32x32x16 MFMA: one wave = 32 q-rows,
// ~45% less LDS read traffic, XOR-swizzled K/V LDS layout at conflict floor.

typedef unsigned short u16;
typedef short bf16x8 __attribute__((ext_vector_type(8)));
typedef float f32x4 __attribute__((ext_vector_type(4)));
typedef float f32x16 __attribute__((ext_vector_type(16)));
typedef unsigned short u16x4 __attribute__((ext_vector_type(4)));

#define S_LEN 2048
#define EMB 1024
#define NH 16
#define HD 64
#define QKV_W 3072
#define BATCH 2
#define CSC 0.18033688f  // 0.125 * log2(e)
#define PSTR 72          // plds row stride (64-wide P rows)

static __device__ __forceinline__ u16 f2bf(float f) {
    unsigned x = __float_as_uint(f);
    return (u16)((x + 0x7fffu + ((x >> 16) & 1u)) >> 16);
}

static __device__ __forceinline__ void gld_lds16(const u16* g, u16* l) {
    __builtin_amdgcn_global_load_lds(
        (const __attribute__((address_space(1))) void*)g,
        (__attribute__((address_space(3))) void*)l, 16, 0, 0);
}

// ---------------- fused fp32 -> bf16 casts (3 ranges) ----------------
#define XN4 (BATCH * S_LEN * EMB / 4)      // 1048576
#define WQ4 (QKV_W * EMB / 4)              // 786432
#define W04 (EMB * EMB / 4)                // 262144
__global__ __launch_bounds__(256) void cvt_all(const float* __restrict__ x,
                                               const float* __restrict__ wq,
                                               const float* __restrict__ w0,
                                               u16* __restrict__ xb,
                                               u16* __restrict__ wqb,
                                               u16* __restrict__ w0b) {
    int i = blockIdx.x * 256 + threadIdx.x;
    const float* src;
    u16* dst;
    int off;
    if (i < XN4) { src = x; dst = xb; off = i; }
    else if (i < XN4 + WQ4) { src = wq; dst = wqb; off = i - XN4; }
    else { src = w0; dst = w0b; off = i - XN4 - WQ4; }
    float4 v = ((const float4*)src)[off];
    u16x4 o;
    o[0] = f2bf(v.x); o[1] = f2bf(v.y); o[2] = f2bf(v.z); o[3] = f2bf(v.w);
    ((u16x4*)dst)[off] = o;
}

// ---------------- GEMM: C[M,N] = A[M,K] @ Bt[N,K]^T ----------------
// BM=128, BN templated, BK=32 (64-B LDS rows = bank-conflict floor).
// Columns n < qcols scaled by CSC (Q pre-scaling for attention).
template <typename OutT, int BN>
__global__ __launch_bounds__(256) void gemm_bt(const u16* __restrict__ A,
                                               const u16* __restrict__ Bt,
                                               OutT* __restrict__ C,
                                               int M, int N, int K, int qcols) {
    constexpr int NF = BN / 32;  // n-frags per wave
    __shared__ alignas(16) u16 As[128 * 32];
    __shared__ alignas(16) u16 Bs[BN * 32];
    const int tid = threadIdx.x;
    const int wave = tid >> 6, lane = tid & 63;
    const int quad = lane >> 4, lr = lane & 15;
    const int m0 = blockIdx.y * 128, n0 = blockIdx.x * BN;
    const int wm = (wave & 1) * 64, wn = (wave >> 1) * (BN / 2);
    const float sc = (n0 < qcols) ? CSC : 1.0f;

    f32x4 acc[4][NF] = {};

    for (int k0 = 0; k0 < K; k0 += 32) {
#pragma unroll
        for (int i = 0; i < 2; ++i) {
            int chunk = tid + i * 256;
            int row = chunk >> 2;
            int col8 = (chunk & 3) * 8;
            gld_lds16(&A[(size_t)(m0 + row) * K + k0 + col8], &As[row * 32 + col8]);
        }
#pragma unroll
        for (int i = 0; i < BN / 64; ++i) {
            int chunk = tid + i * 256;
            int row = chunk >> 2;
            int col8 = (chunk & 3) * 8;
            gld_lds16(&Bt[(size_t)(n0 + row) * K + k0 + col8], &Bs[row * 32 + col8]);
        }
        __syncthreads();
        bf16x8 af[4], bf[NF];
#pragma unroll
        for (int i = 0; i < 4; ++i)
            af[i] = *(const bf16x8*)&As[(wm + i * 16 + lr) * 32 + quad * 8];
#pragma unroll
        for (int i = 0; i < NF; ++i)
            bf[i] = *(const bf16x8*)&Bs[(wn + i * 16 + lr) * 32 + quad * 8];
#pragma unroll
        for (int mi = 0; mi < 4; ++mi)
#pragma unroll
            for (int ni = 0; ni < NF; ++ni)
                acc[mi][ni] = __builtin_amdgcn_mfma_f32_16x16x32_bf16(
                    af[mi], bf[ni], acc[mi][ni], 0, 0, 0);
        __syncthreads();
    }

#pragma unroll
    for (int mi = 0; mi < 4; ++mi) {
#pragma unroll
        for (int r = 0; r < 4; ++r) {
            int gr = m0 + wm + mi * 16 + quad * 4 + r;
#pragma unroll
            for (int ni = 0; ni < NF; ++ni) {
                int gc = n0 + wn + ni * 16 + lr;
                float v = acc[mi][ni][r] * sc;
                if constexpr (sizeof(OutT) == 2)
                    C[(size_t)gr * N + gc] = (OutT)f2bf(v);
                else
                    C[(size_t)gr * N + gc] = (OutT)v;
            }
        }
    }
}

// ---------------- V transpose: qkv[.,2048+h*64+d] -> vt[bh][d][s] ----------------
__global__ __launch_bounds__(256) void transpose_v(const u16* __restrict__ qkv,
                                                   u16* __restrict__ vt) {
    __shared__ alignas(16) u16 t[64][72];
    const int s0 = blockIdx.x * 64;
    const int bh = blockIdx.y;
    const int b = bh >> 4, h = bh & 15;
#pragma unroll
    for (int i = 0; i < 2; ++i) {
        int chunk = threadIdx.x + i * 256;
        int row = chunk >> 3;
        int c8 = (chunk & 7) * 8;
        uint4 v = *(const uint4*)&qkv[(size_t)(b * S_LEN + s0 + row) * QKV_W +
                                      2 * EMB + h * HD + c8];
        const u16* p = (const u16*)&v;
#pragma unroll
        for (int jj = 0; jj < 8; ++jj) t[c8 + jj][row] = p[jj];
    }
    __syncthreads();
#pragma unroll
    for (int i = 0; i < 2; ++i) {
        int chunk = threadIdx.x + i * 256;
        int d = chunk >> 3;
        int c8 = (chunk & 7) * 8;
        uint4 v = *(const uint4*)&t[d][c8];
        *(uint4*)&vt[((size_t)bh * HD + d) * S_LEN + s0 + c8] = v;
    }
}

// ---------------- Flash attention (causal), R12: 32x32x16 MFMA ----------------
// grid (16, 32), 256 thr = 4 waves. Pairing {pi, 31-pi} + flip swizzle.
// Waves 0-1: tile A (q-rows pi*64 + w*32), waves 2-3: tile B. Each wave
// owns 32 q-rows. Ks/Vs: [half][row][4 chunks of 8 u16], chunk position
// XOR-swizzled by (row&3) -> all b128 reads at the bank-conflict floor.
// S^T orientation: mfma(A=K, B=Q) -> lane holds q=lane&31 fixed.
// C/D map: col=lane&31, row=(reg&3)+8*(reg>>2)+4*(lane>>5).
__global__ __launch_bounds__(256, 2) void attn(const u16* __restrict__ qkv,
                                               const u16* __restrict__ vt,
                                               u16* __restrict__ e) {
    const int tid = threadIdx.x;
    const int w = tid >> 6, lane = tid & 63;
    const int lo = lane & 31, hi = lane >> 5;
    const int bx = blockIdx.x, by = blockIdx.y;
    const int flip = (by >> 4) & 1;
    const int pi = flip ? (15 - bx) : bx;
    const int bh = ((by & 15) << 1) | flip;
    const int qtB = 31 - pi;
    const int b = bh >> 4, h = bh & 15;
    const int myqt = (w < 2) ? pi : qtB;
    const int qb = myqt * 64 + (w & 1) * 32;  // this wave's first q row

    __shared__ alignas(16) u16 Ks[2][4096];  // [buf]: [dhalf][kv row][32, XOR-swz]
    __shared__ alignas(16) u16 Vs[2][4096];  // [buf]: [kvhalf][d row][32, XOR-swz]
    __shared__ alignas(16) u16 plds[4][32 * PSTR];
    u16* pw = plds[w];

    const u16* qkv_b = qkv + (size_t)b * S_LEN * QKV_W;
    // Q frags (registers): B-operand layout == per-lane Q[qb+lo][s*16+hi*8+j]
    const u16* qrow = qkv_b + (size_t)(qb + lo) * QKV_W + h * HD;
    bf16x8 qf[4];
#pragma unroll
    for (int s = 0; s < 4; ++s) qf[s] = *(const bf16x8*)(qrow + s * 16 + hi * 8);

    const u16* kbase = qkv_b + EMB + h * HD;          // K[s][d], stride 3072
    const u16* vbase = vt + (size_t)bh * HD * S_LEN;  // V^T[d][s], stride 2048

    f32x16 oacc[2] = {};
    float lsum = 0.f;
    const int qg = qb + lo;

    // staging: thread stages LDS chunk tid (16 B) = (row=tid>>2, cpos=tid&3);
    // content = global chunk (cpos ^ (row&3)) of that row (XOR swizzle).
    const int srow = tid >> 2;
    const int scg = ((tid & 3) ^ (srow & 3)) * 8;  // swizzled source chunk

    auto stage = [&](int j, int bb) {
        const int kv0 = j * 64;
        gld_lds16(kbase + (size_t)(kv0 + srow) * QKV_W + scg, &Ks[bb][tid * 8]);
        gld_lds16(kbase + (size_t)(kv0 + srow) * QKV_W + 32 + scg,
                  &Ks[bb][2048 + tid * 8]);
        gld_lds16(vbase + (size_t)srow * S_LEN + kv0 + scg, &Vs[bb][tid * 8]);
        gld_lds16(vbase + (size_t)srow * S_LEN + kv0 + 32 + scg,
                  &Vs[bb][2048 + tid * 8]);
    };

    stage(0, 0);
    for (int j = 0; j <= qtB; ++j) {
        const int bb = j & 1;
        __syncthreads();  // staged buf bb complete
        if (j < qtB) stage(j + 1, 1 - bb);
        if (j <= myqt) {
            const int kv0 = j * 64;
            const u16* ks = Ks[bb];
            const u16* vs = Vs[bb];
            // ---- S^T = K·Q : sac[ntk][reg] = S[kv0+ntk*32+mrow][qb+lo] ----
            f32x16 sac[2];
#pragma unroll
            for (int ntk = 0; ntk < 2; ++ntk) {
                f32x16 z = {};
#pragma unroll
                for (int s = 0; s < 4; ++s) {
                    int cg = s * 2 + hi;                   // 8-u16 chunk in 64-d row
                    int row = ntk * 32 + lo;
                    bf16x8 kf = *(const bf16x8*)&ks[(cg >> 2) * 2048 + row * 32 +
                                                    (((cg & 3) ^ (row & 3)) * 8)];
                    z = __builtin_amdgcn_mfma_f32_32x32x16_bf16(kf, qf[s], z, 0, 0, 0);
                }
                sac[ntk] = z;
            }
            // ---- softmax: p = exp2(s); mask on diagonal tile ----
            const bool diag = (j == myqt);
            __builtin_amdgcn_wave_barrier();
#pragma unroll
            for (int ntk = 0; ntk < 2; ++ntk) {
#pragma unroll
                for (int g = 0; g < 4; ++g) {
                    float p[4];
#pragma unroll
                    for (int rr = 0; rr < 4; ++rr) {
                        int kv = kv0 + ntk * 32 + 8 * g + 4 * hi + rr;
                        float pv = exp2f(sac[ntk][g * 4 + rr]);
                        if (diag) pv = (kv > qg) ? 0.f : pv;
                        p[rr] = pv;
                    }
                    lsum += (p[0] + p[1]) + (p[2] + p[3]);
                    uint2 pk;  // truncation pack
                    pk.x = __builtin_amdgcn_perm(__float_as_uint(p[1]),
                                                 __float_as_uint(p[0]), 0x07060302u);
                    pk.y = __builtin_amdgcn_perm(__float_as_uint(p[3]),
                                                 __float_as_uint(p[2]), 0x07060302u);
                    *(uint2*)&pw[lo * PSTR + ntk * 32 + 8 * g + 4 * hi] = pk;
                }
            }
            __builtin_amdgcn_wave_barrier();
            // ---- O += P·V : A=P frags, B=V^T frags ----
            bf16x8 pf[4];
#pragma unroll
            for (int s2 = 0; s2 < 4; ++s2)
                pf[s2] = *(const bf16x8*)&pw[lo * PSTR + s2 * 16 + hi * 8];
#pragma unroll
            for (int ntd = 0; ntd < 2; ++ntd) {
#pragma unroll
                for (int s2 = 0; s2 < 4; ++s2) {
                    int cg = s2 * 2 + hi;
                    int row = ntd * 32 + lo;
                    bf16x8 vf = *(const bf16x8*)&vs[(cg >> 2) * 2048 + row * 32 +
                                                    (((cg & 3) ^ (row & 3)) * 8)];
                    oacc[ntd] = __builtin_amdgcn_mfma_f32_32x32x16_bf16(
                        pf[s2], vf, oacc[ntd], 0, 0, 0);
                }
            }
        }
    }

    // ---- finalize: l[q=lo] = lsum + partner-half; e = O / l ----
    float lf = lsum + __shfl_xor(lsum, 32, 64);
    float inv[4][4];
#pragma unroll
    for (int g = 0; g < 4; ++g)
#pragma unroll
        for (int rr = 0; rr < 4; ++rr)
            inv[g][rr] = 1.0f / __shfl(lf, rr + 8 * g + 4 * hi, 64);
#pragma unroll
    for (int ntd = 0; ntd < 2; ++ntd) {
#pragma unroll
        for (int g = 0; g < 4; ++g) {
#pragma unroll
            for (int rr = 0; rr < 4; ++rr) {
                int ql = rr + 8 * g + 4 * hi;
                size_t row = (size_t)(b * S_LEN + qb + ql) * EMB + h * HD;
                e[row + ntd * 32 + lo] = f2bf(oacc[ntd][g * 4 + rr] * inv[g][rr]);
            }
        }
    }
}

// ---------------- launcher ----------------
extern "C" void kernel_launch(void* const* d_in, const int* in_sizes, int n_in,
                              void* d_out, int out_size, void* d_ws, size_t ws_size,
                              hipStream_t stream) {
    const float* x = (const float*)d_in[0];
    const float* w_qkv = (const float*)d_in[1];
    const float* w0 = (const float*)d_in[2];
    float* out = (float*)d_out;

    const size_t M = (size_t)BATCH * S_LEN;  // 4096
    u16* xb = (u16*)d_ws;
    u16* wqb = xb + M * EMB;
    u16* w0b = wqb + (size_t)QKV_W * EMB;
    u16* qkvb = w0b + (size_t)EMB * EMB;
    u16* vtb = qkvb + M * QKV_W;
    u16* eb = vtb + (size_t)BATCH * NH * HD * S_LEN;

    cvt_all<<<(XN4 + WQ4 + W04) / 256, 256, 0, stream>>>(x, w_qkv, w0, xb, wqb, w0b);

    // qkv = x @ w_qkv^T; Q columns pre-scaled by CSC (BK=32: conflict floor)
    gemm_bt<u16, 128><<<dim3(QKV_W / 128, M / 128), 256, 0, stream>>>(
        xb, wqb, qkvb, (int)M, QKV_W, EMB, EMB);

    transpose_v<<<dim3(S_LEN / 64, BATCH * NH), 256, 0, stream>>>(qkvb, vtb);

    attn<<<dim3(16, BATCH * NH), 256, 0, stream>>>(qkvb, vtb, eb);

    // out = e @ w0^T (128x64 tiles, BK=32)
    gemm_bt<float, 64><<<dim3(EMB / 64, M / 128), 256, 0, stream>>>(
        eb, w0b, out, (int)M, EMB, EMB, 0);
}